// Round 9
// baseline (116.149 us; speedup 1.0000x reference)
//
#include <hip/hip_runtime.h>
#include <hip/hip_bf16.h>

// GATv2 on MI355X. G=80, N=1000, F=C=64, H=1, E=8000 (+N self loops). fp32 in/out.
// Harness tax ~78-90us (268MB ws 0xAA poison ~45us + out poison + restores + gaps).
// R9: graph-major agg — XLt[:,g,:] (125KB) staged once into 144KB dynamic LDS per
// block (CDNA4 160KB LDS), octet-per-dst with shfl-distributed CSR srcs and batched
// ds_read_b128 gathers. Kills the 92MB random LLC gather of R5-R8.

#define GG 80
#define NN 1000
#define EE 8000
#define MM 80000           // G*N rows
#define PAD 40             // padded CSR row stride (ints): [0]=cnt, [1..cnt]=srcs
#define NEG_SLOPE 0.2f

typedef __attribute__((ext_vector_type(8))) short short8;    // 8 bf16 = 4 VGPRs
typedef __attribute__((ext_vector_type(4))) float floatx4;   // MFMA C/D

__device__ __forceinline__ unsigned short f2b(float f) {     // fp32 -> bf16 bits, RNE
    unsigned int u = __float_as_uint(f);
    unsigned int r = u + 0x7fffu + ((u >> 16) & 1u);
    return (unsigned short)(r >> 16);
}

// ---------------- Fused: blocks 0..312 = MFMA projection, block 313 = padded CSR ----------------
__global__ __launch_bounds__(256) void proj_csr_kernel(
    const float* __restrict__ x,
    const float* __restrict__ wl,
    const float* __restrict__ wr,
    const int* __restrict__ ei32,
    unsigned short* __restrict__ XLt,
    unsigned short* __restrict__ XRt,
    int* __restrict__ list2)
{
    __shared__ __align__(16) unsigned short Wt[128 * 72];  // proj: W [col][k], pad 72
    __shared__ int cnt[1024];                              // csr: per-dst counters
    const int t = threadIdx.x;

    if (blockIdx.x == 313) {
        // ---- padded CSR: count via LDS atomics, write directly (no scan) ----
        int oddw = ei32[2 * t + 1];                        // idx<=511 in-bounds both widths
        const int stride = __any(oddw != 0) ? 1 : 2;       // int64(LE) => odd words zero

        for (int i = t; i < 1024; i += 256) cnt[i] = 0;
        __syncthreads();

        int dv[32], sv[32];
#pragma unroll
        for (int k = 0; k < 32; k++) {
            int e = t + (k << 8);
            dv[k] = (e < EE) ? ei32[(size_t)(EE + e) * stride] : -1;
        }
#pragma unroll
        for (int k = 0; k < 32; k++) {
            int e = t + (k << 8);
            sv[k] = (e < EE) ? ei32[(size_t)e * stride] : 0;
        }
#pragma unroll
        for (int k = 0; k < 32; k++) {
            if (dv[k] >= 0) {
                int pos = atomicAdd(&cnt[dv[k]], 1);
                if (pos < PAD - 2) list2[dv[k] * PAD + 1 + pos] = sv[k];
            }
        }
        __syncthreads();
        for (int n = t; n < NN; n += 256) {
            int c = min(cnt[n], PAD - 2);
            list2[n * PAD + 1 + c] = n;                    // self loop appended
            list2[n * PAD] = c + 1;                        // count
        }
        return;
    }

    // ---- MFMA projection (proven R4): wave handles 64 rows, N=128 (wl||wr) ----
    for (int idx = t; idx < 8192; idx += 256) {
        int half = idx >> 12;
        int k = (idx & 4095) >> 6;
        int c = idx & 63;
        float v = half ? wr[k * 64 + c] : wl[k * 64 + c];
        Wt[(c + half * 64) * 72 + k] = f2b(v);
    }
    __syncthreads();

    const int wave = t >> 6;
    const int lane = t & 63;
    const int quad = lane >> 4;
    const int lm   = lane & 15;
    const int Rb   = (blockIdx.x * 4 + wave) * 64;

    short8 Bf[2][8];
#pragma unroll
    for (int ks = 0; ks < 2; ks++)
#pragma unroll
        for (int sub = 0; sub < 8; sub++)
            Bf[ks][sub] = *(const short8*)(&Wt[(sub * 16 + lm) * 72 + ks * 32 + quad * 8]);

    const float4* x4 = (const float4*)x;

#pragma unroll
    for (int sm = 0; sm < 4; sm++) {
        const int rbase = Rb + sm * 16;
        const int r  = rbase + lm;
        const int rc = (r < MM) ? r : (MM - 1);

        short8 Af[2];
#pragma unroll
        for (int ks = 0; ks < 2; ks++) {
            float4 p = x4[(size_t)rc * 16 + ks * 8 + quad * 2];
            float4 q = x4[(size_t)rc * 16 + ks * 8 + quad * 2 + 1];
            short8 a;
            a[0] = (short)f2b(p.x); a[1] = (short)f2b(p.y);
            a[2] = (short)f2b(p.z); a[3] = (short)f2b(p.w);
            a[4] = (short)f2b(q.x); a[5] = (short)f2b(q.y);
            a[6] = (short)f2b(q.z); a[7] = (short)f2b(q.w);
            Af[ks] = a;
        }

        floatx4 acc[8];
#pragma unroll
        for (int sub = 0; sub < 8; sub++) acc[sub] = (floatx4)(0.f);
#pragma unroll
        for (int ks = 0; ks < 2; ks++)
#pragma unroll
            for (int sub = 0; sub < 8; sub++)
                acc[sub] = __builtin_amdgcn_mfma_f32_16x16x32_bf16(Af[ks], Bf[ks][sub], acc[sub], 0, 0, 0);

#pragma unroll
        for (int reg = 0; reg < 4; reg++) {
            int rr = rbase + quad * 4 + reg;
            if (rr < MM) {
                int g = rr / 1000;
                int n = rr - g * 1000;
                size_t ob = ((size_t)n * GG + g) * 64 + lm;
#pragma unroll
                for (int sub = 0; sub < 4; sub++)
                    XLt[ob + sub * 16] = f2b(acc[sub][reg]);
#pragma unroll
                for (int sub = 4; sub < 8; sub++)
                    XRt[ob + (sub - 4) * 16] = f2b(acc[sub][reg]);
            }
        }
    }
}

// ---------------- Aggregation: grid (80 g, 3 parts), 512 thr, XL g-slice in LDS ----------------
// Stage sXL[n][72] (144 KB dynamic). Octet (8 lanes) per dst d; per d: header+XRt
// issued parallel, srcs via intra-octet shfl, batched ds_read_b128, masked tail.
__global__ __launch_bounds__(512) void agg_kernel(
    const unsigned short* __restrict__ XLt,
    const unsigned short* __restrict__ XRt,
    const int* __restrict__ list2,
    const float* __restrict__ att,
    const float* __restrict__ bias,
    float* __restrict__ out)
{
    extern __shared__ unsigned short sXL[];    // [1000][72] bf16, 144000 B
    const int t = threadIdx.x;
    const int g = blockIdx.x;
    const int lane = t & 63;
    const int base = lane & ~7;                // octet base lane (within wave)
    const int cg = t & 7;
    const int octg = t >> 3;                   // 0..63

    // ---- stage XLt[:,g,:] coalesced: 16 rounds x (64 rows x 128 B) ----
#pragma unroll
    for (int i = 0; i < 16; i++) {
        int n = i * 64 + octg;
        if (n < NN) {
            uint4 v = *(const uint4*)(XLt + ((size_t)n * GG + g) * 64 + cg * 8);
            *(uint4*)(&sXL[n * 72 + cg * 8]) = v;
        }
    }

    float av[8], avn[8], bv[8];
#pragma unroll
    for (int j = 0; j < 8; j++) {
        av[j]  = att[cg * 8 + j];
        avn[j] = av[j] * NEG_SLOPE;
        bv[j]  = bias[cg * 8 + j];
    }
    __syncthreads();

    const int dstart = blockIdx.y * 334;
    const int dend   = min(dstart + 334, NN);

    for (int d = dstart + octg; d < dend; d += 64) {
        // header batch 0 + XR row: independent, issued together
        int hv = list2[d * PAD + cg];
        uint4 uxr = *(const uint4*)(XRt + ((size_t)d * GG + g) * 64 + cg * 8);
        int cnt = __shfl(hv, base, 64);
        cnt = min(cnt, PAD - 1);

        float xr[8];
        {
            const unsigned int uw[4] = {uxr.x, uxr.y, uxr.z, uxr.w};
#pragma unroll
            for (int q = 0; q < 4; q++) {
                xr[2 * q]     = __uint_as_float(uw[q] << 16);
                xr[2 * q + 1] = __uint_as_float(uw[q] & 0xffff0000u);
            }
        }

        float acc[8];
#pragma unroll
        for (int j = 0; j < 8; j++) acc[j] = 0.f;
        float dn = 0.f;

        // batches: b=0 carries cnt + srcs[0..6]; b>=1 carries srcs[8b-1 .. 8b+6]
        int lo = 0, nsrc = 7, joff = 1;
        for (int b = 0; lo < cnt; b++) {
            if (b > 0) {
                hv = list2[d * PAD + b * 8 + cg];   // next 8 srcs
                nsrc = 8; joff = 0;
            }
            uint4 u[8];
#pragma unroll
            for (int j = 0; j < 8; j++) {
                if (j < nsrc) {
                    int sl = __shfl(hv, base + joff + j, 64);
                    int s = (lo + j < cnt) ? sl : 0;   // clamp tail garbage
                    u[j] = *(const uint4*)(&sXL[s * 72 + cg * 8]);
                }
            }
#pragma unroll
            for (int j = 0; j < 8; j++) {
                if (j < nsrc) {
                    const unsigned int uw[4] = {u[j].x, u[j].y, u[j].z, u[j].w};
                    float xf[8];
#pragma unroll
                    for (int q = 0; q < 4; q++) {
                        xf[2 * q]     = __uint_as_float(uw[q] << 16);
                        xf[2 * q + 1] = __uint_as_float(uw[q] & 0xffff0000u);
                    }
                    float p = 0.f;
#pragma unroll
                    for (int c = 0; c < 8; c++) {
                        float v = xf[c] + xr[c];
                        p = fmaf(av[c], fmaxf(v, 0.f), p);
                        p = fmaf(avn[c], fminf(v, 0.f), p);
                    }
                    p += __shfl_xor(p, 1, 64);
                    p += __shfl_xor(p, 2, 64);
                    p += __shfl_xor(p, 4, 64);
                    float w = (lo + j < cnt) ? __expf(p) : 0.f;  // octet-uniform mask
                    dn += w;
#pragma unroll
                    for (int c = 0; c < 8; c++) acc[c] = fmaf(w, xf[c], acc[c]);
                }
            }
            lo += nsrc;
        }

        const float inv = 1.f / dn;
        float4 r0, r1;
        r0.x = acc[0] * inv + bv[0];
        r0.y = acc[1] * inv + bv[1];
        r0.z = acc[2] * inv + bv[2];
        r0.w = acc[3] * inv + bv[3];
        r1.x = acc[4] * inv + bv[4];
        r1.y = acc[5] * inv + bv[5];
        r1.z = acc[6] * inv + bv[6];
        r1.w = acc[7] * inv + bv[7];
        float* po = out + ((size_t)g * NN + d) * 64 + cg * 8;
        *(float4*)po = r0;
        *(float4*)(po + 4) = r1;
    }
}

extern "C" void kernel_launch(void* const* d_in, const int* in_sizes, int n_in,
                              void* d_out, int out_size, void* d_ws, size_t ws_size,
                              hipStream_t stream) {
    const float* x    = (const float*)d_in[0];
    const int*   ei   = (const int*)d_in[1];
    const float* wl   = (const float*)d_in[2];
    const float* wr   = (const float*)d_in[3];
    const float* att  = (const float*)d_in[4];
    const float* bias = (const float*)d_in[5];
    float* out = (float*)d_out;

    char* ws = (char*)d_ws;
    int* list2 = (int*)ws;                                   // 1000*40 ints = 160 KB
    unsigned short* XLt = (unsigned short*)(ws + 262144);    // [N][G][64] bf16 = 10.24 MB
    unsigned short* XRt = XLt + (size_t)NN * GG * 64;        // + 10.24 MB

    hipLaunchKernelGGL(proj_csr_kernel, dim3(314), dim3(256), 0, stream,
                       x, wl, wr, ei, XLt, XRt, list2);
    hipLaunchKernelGGL(agg_kernel, dim3(GG, 3), dim3(512), 144000, stream,
                       XLt, XRt, list2, att, bias, out);
}

// Round 10
// 113.270 us; speedup vs baseline: 1.0254x; 1.0254x over previous
//
#include <hip/hip_runtime.h>
#include <hip/hip_bf16.h>

// GATv2 on MI355X. G=80, N=1000, F=C=64, H=1, E=8000 (+N self loops). fp32 in/out.
// R10 = R8 verbatim (best measured: 113.8us). R9's LDS-staged agg regressed (+2.3us):
// 144KB LDS -> 1 block/CU -> occupancy loss outweighs LDS-vs-LLC gather latency.
// Ledger: harness ~90us immovable (45us ws-poison fill at 75% HBM peak + out poison +
// restores + gaps); proj_csr ~7us ~= its 41MB BW floor; agg ~14us vs ~10us floor
// (2 dependent cold rounds + 5us VALU floor + 20.5MB out write).

#define GG 80
#define NN 1000
#define EE 8000
#define MM 80000           // G*N rows
#define PAD 40             // padded CSR row stride (ints): [0]=cnt, [1..cnt]=srcs
#define NEG_SLOPE 0.2f

typedef __attribute__((ext_vector_type(8))) short short8;    // 8 bf16 = 4 VGPRs
typedef __attribute__((ext_vector_type(4))) float floatx4;   // MFMA C/D

__device__ __forceinline__ unsigned short f2b(float f) {     // fp32 -> bf16 bits, RNE
    unsigned int u = __float_as_uint(f);
    unsigned int r = u + 0x7fffu + ((u >> 16) & 1u);
    return (unsigned short)(r >> 16);
}

// ---------------- Fused: blocks 0..312 = MFMA projection, block 313 = padded CSR ----------------
__global__ __launch_bounds__(256) void proj_csr_kernel(
    const float* __restrict__ x,
    const float* __restrict__ wl,
    const float* __restrict__ wr,
    const int* __restrict__ ei32,
    unsigned short* __restrict__ XLt,
    unsigned short* __restrict__ XRt,
    int* __restrict__ list2)
{
    __shared__ __align__(16) unsigned short Wt[128 * 72];  // proj: W [col][k], pad 72
    __shared__ int cnt[1024];                              // csr: per-dst counters
    const int t = threadIdx.x;

    if (blockIdx.x == 313) {
        // ---- padded CSR: count via LDS atomics, write directly (no scan) ----
        int oddw = ei32[2 * t + 1];                        // idx<=511 in-bounds both widths
        const int stride = __any(oddw != 0) ? 1 : 2;       // int64(LE) => odd words zero

        for (int i = t; i < 1024; i += 256) cnt[i] = 0;
        __syncthreads();

        int dv[32], sv[32];
#pragma unroll
        for (int k = 0; k < 32; k++) {
            int e = t + (k << 8);
            dv[k] = (e < EE) ? ei32[(size_t)(EE + e) * stride] : -1;
        }
#pragma unroll
        for (int k = 0; k < 32; k++) {
            int e = t + (k << 8);
            sv[k] = (e < EE) ? ei32[(size_t)e * stride] : 0;
        }
#pragma unroll
        for (int k = 0; k < 32; k++) {
            if (dv[k] >= 0) {
                int pos = atomicAdd(&cnt[dv[k]], 1);
                if (pos < PAD - 2) list2[dv[k] * PAD + 1 + pos] = sv[k];
            }
        }
        __syncthreads();
        for (int n = t; n < NN; n += 256) {
            int c = min(cnt[n], PAD - 2);
            list2[n * PAD + 1 + c] = n;                    // self loop appended
            list2[n * PAD] = c + 1;                        // count
        }
        return;
    }

    // ---- MFMA projection (proven R4): wave handles 64 rows, N=128 (wl||wr) ----
    for (int idx = t; idx < 8192; idx += 256) {
        int half = idx >> 12;                 // 0: wl, 1: wr
        int k = (idx & 4095) >> 6;
        int c = idx & 63;
        float v = half ? wr[k * 64 + c] : wl[k * 64 + c];
        Wt[(c + half * 64) * 72 + k] = f2b(v);
    }
    __syncthreads();

    const int wave = t >> 6;
    const int lane = t & 63;
    const int quad = lane >> 4;
    const int lm   = lane & 15;
    const int Rb   = (blockIdx.x * 4 + wave) * 64;

    short8 Bf[2][8];
#pragma unroll
    for (int ks = 0; ks < 2; ks++)
#pragma unroll
        for (int sub = 0; sub < 8; sub++)
            Bf[ks][sub] = *(const short8*)(&Wt[(sub * 16 + lm) * 72 + ks * 32 + quad * 8]);

    const float4* x4 = (const float4*)x;

#pragma unroll
    for (int sm = 0; sm < 4; sm++) {
        const int rbase = Rb + sm * 16;
        const int r  = rbase + lm;
        const int rc = (r < MM) ? r : (MM - 1);

        short8 Af[2];
#pragma unroll
        for (int ks = 0; ks < 2; ks++) {
            float4 p = x4[(size_t)rc * 16 + ks * 8 + quad * 2];
            float4 q = x4[(size_t)rc * 16 + ks * 8 + quad * 2 + 1];
            short8 a;
            a[0] = (short)f2b(p.x); a[1] = (short)f2b(p.y);
            a[2] = (short)f2b(p.z); a[3] = (short)f2b(p.w);
            a[4] = (short)f2b(q.x); a[5] = (short)f2b(q.y);
            a[6] = (short)f2b(q.z); a[7] = (short)f2b(q.w);
            Af[ks] = a;
        }

        floatx4 acc[8];
#pragma unroll
        for (int sub = 0; sub < 8; sub++) acc[sub] = (floatx4)(0.f);
#pragma unroll
        for (int ks = 0; ks < 2; ks++)
#pragma unroll
            for (int sub = 0; sub < 8; sub++)
                acc[sub] = __builtin_amdgcn_mfma_f32_16x16x32_bf16(Af[ks], Bf[ks][sub], acc[sub], 0, 0, 0);

#pragma unroll
        for (int reg = 0; reg < 4; reg++) {
            int rr = rbase + quad * 4 + reg;
            if (rr < MM) {
                int g = rr / 1000;
                int n = rr - g * 1000;
                size_t ob = ((size_t)n * GG + g) * 64 + lm;
#pragma unroll
                for (int sub = 0; sub < 4; sub++)
                    XLt[ob + sub * 16] = f2b(acc[sub][reg]);
#pragma unroll
                for (int sub = 4; sub < 8; sub++)
                    XRt[ob + (sub - 4) * 16] = f2b(acc[sub][reg]);
            }
        }
    }
}

// ---------------- Aggregation: grid (1000, 5), block 128 thr = 16 graphs x 8 cgroups ----------------
// Round A (parallel, independent): header row (40 ints), xr uint4, att, bias.
// Round B: one x16-ILP gather (avg cnt 9 -> single round 99%). Softmax without
// max-shift (logits bounded) => associative weighted sum; tail masked w=0.
__global__ __launch_bounds__(128) void agg_kernel(
    const unsigned short* __restrict__ XLt,
    const unsigned short* __restrict__ XRt,
    const int* __restrict__ list2,
    const float* __restrict__ att,
    const float* __restrict__ bias,
    float* __restrict__ out)
{
    __shared__ int sh[PAD];
    const int t = threadIdx.x;
    const int d = blockIdx.x;
    const int g = blockIdx.y * 16 + (t >> 3);
    const int cg = t & 7;

    if (t < PAD) sh[t] = list2[d * PAD + t];   // header: cnt + srcs

    float xr[8], av[8], bv[8];
    {
        const uint4 u = *(const uint4*)(XRt + ((size_t)d * GG + g) * 64 + cg * 8);
        const unsigned int uw[4] = {u.x, u.y, u.z, u.w};
#pragma unroll
        for (int q = 0; q < 4; q++) {
            xr[2 * q + 0] = __uint_as_float(uw[q] << 16);
            xr[2 * q + 1] = __uint_as_float(uw[q] & 0xffff0000u);
        }
#pragma unroll
        for (int j = 0; j < 8; j++) { av[j] = att[cg * 8 + j]; bv[j] = bias[cg * 8 + j]; }
    }
    __syncthreads();
    const int cnt = sh[0];

    float acc[8];
#pragma unroll
    for (int j = 0; j < 8; j++) acc[j] = 0.f;
    float dn = 0.f;

    for (int i = 0; i < cnt; i += 16) {
        uint4 u[16];
#pragma unroll
        for (int e = 0; e < 16; e++) {
            int idx = i + e;
            int s = sh[1 + ((idx < cnt) ? idx : 0)];
            u[e] = *(const uint4*)(XLt + ((size_t)s * GG + g) * 64 + cg * 8);
        }
#pragma unroll
        for (int e = 0; e < 16; e++) {
            const unsigned int uw[4] = {u[e].x, u[e].y, u[e].z, u[e].w};
            float xf[8];
#pragma unroll
            for (int q = 0; q < 4; q++) {
                xf[2 * q]     = __uint_as_float(uw[q] << 16);
                xf[2 * q + 1] = __uint_as_float(uw[q] & 0xffff0000u);
            }
            float p = 0.f;
#pragma unroll
            for (int j = 0; j < 8; j++) {
                float v = xf[j] + xr[j];
                float lv = fmaxf(v, 0.f) + NEG_SLOPE * fminf(v, 0.f);
                p = fmaf(av[j], lv, p);
            }
            p += __shfl_xor(p, 1, 64);
            p += __shfl_xor(p, 2, 64);
            p += __shfl_xor(p, 4, 64);
            float w = (i + e < cnt) ? __expf(p) : 0.f;   // block-uniform mask
            dn += w;
#pragma unroll
            for (int j = 0; j < 8; j++) acc[j] = fmaf(w, xf[j], acc[j]);
        }
    }

    const float inv = 1.f / dn;
    float4 r0, r1;
    r0.x = acc[0] * inv + bv[0];
    r0.y = acc[1] * inv + bv[1];
    r0.z = acc[2] * inv + bv[2];
    r0.w = acc[3] * inv + bv[3];
    r1.x = acc[4] * inv + bv[4];
    r1.y = acc[5] * inv + bv[5];
    r1.z = acc[6] * inv + bv[6];
    r1.w = acc[7] * inv + bv[7];
    float* po = out + ((size_t)g * NN + d) * 64 + cg * 8;
    *(float4*)po = r0;
    *(float4*)(po + 4) = r1;
}

extern "C" void kernel_launch(void* const* d_in, const int* in_sizes, int n_in,
                              void* d_out, int out_size, void* d_ws, size_t ws_size,
                              hipStream_t stream) {
    const float* x    = (const float*)d_in[0];
    const int*   ei   = (const int*)d_in[1];
    const float* wl   = (const float*)d_in[2];
    const float* wr   = (const float*)d_in[3];
    const float* att  = (const float*)d_in[4];
    const float* bias = (const float*)d_in[5];
    float* out = (float*)d_out;

    char* ws = (char*)d_ws;
    int* list2 = (int*)ws;                                   // 1000*40 ints = 160 KB
    unsigned short* XLt = (unsigned short*)(ws + 262144);    // [N][G][64] bf16 = 10.24 MB
    unsigned short* XRt = XLt + (size_t)NN * GG * 64;        // + 10.24 MB

    hipLaunchKernelGGL(proj_csr_kernel, dim3(314), dim3(256), 0, stream,
                       x, wl, wr, ei, XLt, XRt, list2);
    hipLaunchKernelGGL(agg_kernel, dim3(NN, 5), dim3(128), 0, stream,
                       XLt, XRt, list2, att, bias, out);
}